// Round 8
// baseline (300.334 us; speedup 1.0000x reference)
//
#include <hip/hip_runtime.h>
#include <hip/hip_bf16.h>

typedef __attribute__((ext_vector_type(4))) int int4v;

#define TOKENS 8192
#define IN_F   4096
#define OUT_F  4096
#define NKT    64              // K-tiles (64 B each)
#define NMF    (TOKENS / 16)   // 512 A fragments per k-tile
#define NNF    (OUT_F / 16)    // 256 B fragments per k-tile

// ws layout (bytes):
//   0     : double hdr[2]  (hdr[0]=mean, hdr[1]=scale)
//   1024  : double partials[1024]
//   9216  : float  xpart[1024]
//   16384 : A' fragment-major int8  [NKT][NMF][64*16]  (33.55 MB)
//   16384+33554432 : B' fragment-major int8 [NKT][NNF][64*16] (16.78 MB)

__global__ __launch_bounds__(256) void k_pre(const float4* __restrict__ w,
                                             const float4* __restrict__ x,
                                             double* __restrict__ partials,
                                             float* __restrict__ xpart) {
  if (blockIdx.x < 1024) {
    __shared__ double sm[256];
    double s = 0.0;
    const float4* p = w + (size_t)blockIdx.x * 4096;
    for (int i = threadIdx.x; i < 4096; i += 256) {
      float4 v = p[i];
      s += (double)v.x + (double)v.y + (double)v.z + (double)v.w;
    }
    sm[threadIdx.x] = s;
    __syncthreads();
    for (int off = 128; off > 0; off >>= 1) {
      if (threadIdx.x < off) sm[threadIdx.x] += sm[threadIdx.x + off];
      __syncthreads();
    }
    if (threadIdx.x == 0) partials[blockIdx.x] = sm[0];
  } else {
    const int b = blockIdx.x - 1024;
    float m = 0.f;
    const size_t n = (size_t)TOKENS * IN_F / 4;
    for (size_t i = (size_t)b * 256 + threadIdx.x; i < n; i += (size_t)1024 * 256) {
      float4 v = x[i];
      m = fmaxf(m, fmaxf(fmaxf(fabsf(v.x), fabsf(v.y)),
                         fmaxf(fabsf(v.z), fabsf(v.w))));
    }
    __shared__ float smf[256];
    smf[threadIdx.x] = m;
    __syncthreads();
    for (int off = 128; off > 0; off >>= 1) {
      if (threadIdx.x < off) smf[threadIdx.x] = fmaxf(smf[threadIdx.x], smf[threadIdx.x + off]);
      __syncthreads();
    }
    if (threadIdx.x == 0) xpart[b] = smf[0];
  }
}

__global__ __launch_bounds__(256) void k_finalize(double* __restrict__ hdr,
                                                  const double* __restrict__ partials,
                                                  const float* __restrict__ xpart) {
  __shared__ double sm[256];
  __shared__ float smf[256];
  double s = partials[threadIdx.x] + partials[threadIdx.x + 256] +
             partials[threadIdx.x + 512] + partials[threadIdx.x + 768];
  float m = fmaxf(fmaxf(xpart[threadIdx.x], xpart[threadIdx.x + 256]),
                  fmaxf(xpart[threadIdx.x + 512], xpart[threadIdx.x + 768]));
  sm[threadIdx.x] = s;
  smf[threadIdx.x] = m;
  __syncthreads();
  for (int off = 128; off > 0; off >>= 1) {
    if (threadIdx.x < off) {
      sm[threadIdx.x] += sm[threadIdx.x + off];
      smf[threadIdx.x] = fmaxf(smf[threadIdx.x], smf[threadIdx.x + off]);
    }
    __syncthreads();
  }
  if (threadIdx.x == 0) {
    hdr[0] = sm[0] / (double)((size_t)OUT_F * IN_F);   // mean of weight
    hdr[1] = 127.0 / (double)smf[0];                   // absmax scale
  }
}

// ---------------------------------------------------------------------------
// Fused quantize/ternarize + fragment-major pack.
// Chunk c (0..63) of fragment f holds row_in_frag = c>>2, k-chunk = c&3:
// 16 int8 of k ∈ [kt*64 + (c&3)*16, +16) for row f*16 + (c>>2).
// GEMM lane l loads chunk (l&15)*4 + (l>>4) -> its MFMA operand slice.
// Each thread reads 64 B contiguous (4 float4) and writes 16 B; consecutive
// threads cover 256 B read segments and fully-coalesced 1 KB writes.
// ---------------------------------------------------------------------------
#define A_PACK_BLK ((NKT * NMF * 64) / 256)   // 8192
#define B_PACK_BLK ((NKT * NNF * 64) / 256)   // 4096

__global__ __launch_bounds__(256) void k_pack(const float4* __restrict__ x,
                                              const float4* __restrict__ w,
                                              int4v* __restrict__ Ap,
                                              int4v* __restrict__ Bp,
                                              const double* __restrict__ hdr) {
  if (blockIdx.x < A_PACK_BLK) {
    const double s = hdr[1];
    const int gid  = blockIdx.x * 256 + threadIdx.x;
    const int cid  = gid & 63;
    const int frag = gid >> 6;          // kt*NMF + mf
    const int kt   = frag >> 9;         // /NMF
    const int mf   = frag & (NMF - 1);
    const int row  = mf * 16 + (cid >> 2);
    const float4* src = x + (size_t)row * 1024 + kt * 16 + (cid & 3) * 4;
    int out[4];
#pragma unroll
    for (int j = 0; j < 4; ++j) {
      float4 v = src[j];
      int a = (int)rint(s * (double)v.x);
      int b = (int)rint(s * (double)v.y);
      int c = (int)rint(s * (double)v.z);
      int d = (int)rint(s * (double)v.w);
      out[j] = (a & 255) | ((b & 255) << 8) | ((c & 255) << 16) | ((d & 255) << 24);
    }
    Ap[gid] = int4v{out[0], out[1], out[2], out[3]};
  } else {
    const double m = hdr[0];
    const int gid  = (blockIdx.x - A_PACK_BLK) * 256 + threadIdx.x;
    const int cid  = gid & 63;
    const int frag = gid >> 6;          // kt*NNF + nf
    const int kt   = frag >> 8;         // /NNF
    const int nf   = frag & (NNF - 1);
    const int row  = nf * 16 + (cid >> 2);
    const float4* src = w + (size_t)row * 1024 + kt * 16 + (cid & 3) * 4;
    int out[4];
#pragma unroll
    for (int j = 0; j < 4; ++j) {
      float4 v = src[j];
      int a = ((double)v.x > m) - ((double)v.x < m);
      int b = ((double)v.y > m) - ((double)v.y < m);
      int c = ((double)v.z > m) - ((double)v.z < m);
      int d = ((double)v.w > m) - ((double)v.w < m);
      out[j] = (a & 255) | ((b & 255) << 8) | ((c & 255) << 16) | ((d & 255) << 24);
    }
    Bp[gid] = int4v{out[0], out[1], out[2], out[3]};
  }
}

// ---------------------------------------------------------------------------
// Zero-LDS int8 GEMM: 256x256 tile, 8 waves (2M x 4N), per-wave 128x64 out.
// Operands are fragment-major, so every fragment load is one contiguous,
// fully-coalesced 1 KB wave load straight from L1/L2/L3. No LDS, no barriers,
// no hand waitcnt: register ping-pong (X/Y), distance-1 prefetch; compiler
// inserts the vmcnt fences from plain dataflow. All frag-array indices are
// compile-time (rule #20).
// ---------------------------------------------------------------------------
#define LD_TILE(A_, B_, KT)                                                     \
  do {                                                                          \
    _Pragma("unroll")                                                           \
    for (int m_ = 0; m_ < 8; ++m_)                                              \
      A_[m_] = *(const int4v*)(aBase + (size_t)(KT) * (NMF * 1024) + m_ * 1024);\
    _Pragma("unroll")                                                           \
    for (int n_ = 0; n_ < 4; ++n_)                                              \
      B_[n_] = *(const int4v*)(bBase + (size_t)(KT) * (NNF * 1024) + n_ * 1024);\
  } while (0)

#define MFMA_TILE(A_, B_)                                                       \
  do {                                                                          \
    _Pragma("unroll")                                                           \
    for (int m_ = 0; m_ < 8; ++m_)                                              \
      _Pragma("unroll")                                                         \
      for (int n_ = 0; n_ < 4; ++n_)                                            \
        acc[m_][n_] = __builtin_amdgcn_mfma_i32_16x16x64_i8(A_[m_], B_[n_],     \
                                                            acc[m_][n_], 0, 0, 0);\
  } while (0)

__global__ __launch_bounds__(512, 2) void k_gemm(const signed char* __restrict__ Ap,
                                                 const signed char* __restrict__ Bp,
                                                 float* __restrict__ out) {
  const int tid  = threadIdx.x;
  const int lane = tid & 63;
  const int wid  = tid >> 6;     // 0..7
  const int wm   = wid >> 2;     // 0..1 -> row offset wm*128
  const int wn   = wid & 3;      // 0..3 -> col offset wn*64
  const int l15  = lane & 15, l4 = lane >> 4;
  const int perm = l15 * 4 + l4; // chunk index inside a fragment

  // XCD-aware swizzle: 512 blocks, 8 XCDs, 64 blocks/XCD chunk (bijective)
  const int swz = (blockIdx.x & 7) * 64 + (blockIdx.x >> 3);
  const int bm = swz >> 4;       // 0..31
  const int bn = swz & 15;       // 0..15

  const int mf0 = bm * 16 + wm * 8;
  const int nf0 = bn * 16 + wn * 4;
  const signed char* aBase = Ap + (size_t)mf0 * 1024 + perm * 16;
  const signed char* bBase = Bp + (size_t)nf0 * 1024 + perm * 16;

  int4v acc[8][4];
#pragma unroll
  for (int i = 0; i < 8; ++i)
#pragma unroll
    for (int j = 0; j < 4; ++j) acc[i][j] = int4v{0, 0, 0, 0};

  int4v aX[8], bX[4], aY[8], bY[4];

  LD_TILE(aX, bX, 0);
  for (int kt = 0; kt < 62; kt += 2) {
    LD_TILE(aY, bY, kt + 1);
    MFMA_TILE(aX, bX);
    LD_TILE(aX, bX, kt + 2);
    MFMA_TILE(aY, bY);
  }
  LD_TILE(aY, bY, 63);
  MFMA_TILE(aX, bX);
  MFMA_TILE(aY, bY);

  // epilogue: C/D mapping col = lane&15, row = (lane>>4)*4 + r
  const size_t row0 = (size_t)bm * 256;
  const size_t col0 = (size_t)bn * 256;
#pragma unroll
  for (int m = 0; m < 8; ++m)
#pragma unroll
    for (int n = 0; n < 4; ++n)
#pragma unroll
      for (int r = 0; r < 4; ++r) {
        const size_t rg = row0 + wm * 128 + m * 16 + l4 * 4 + r;
        const size_t cg = col0 + wn * 64 + n * 16 + l15;
        out[rg * OUT_F + cg] = (float)acc[m][n][r];
      }
}

extern "C" void kernel_launch(void* const* d_in, const int* in_sizes, int n_in,
                              void* d_out, int out_size, void* d_ws, size_t ws_size,
                              hipStream_t stream) {
  const float* x = (const float*)d_in[0];   // input  [8192][4096] f32
  const float* w = (const float*)d_in[1];   // weight [4096][4096] f32
  float* out = (float*)d_out;               // [8192][4096] f32

  char* ws = (char*)d_ws;
  double*   hdr      = (double*)ws;
  double*   partials = (double*)(ws + 1024);
  float*    xpart    = (float*)(ws + 9216);
  signed char* Apb   = (signed char*)(ws + 16384);
  signed char* Bpb   = (signed char*)(ws + 16384 + (size_t)TOKENS * IN_F);

  k_pre<<<2048, 256, 0, stream>>>((const float4*)w, (const float4*)x, partials, xpart);
  k_finalize<<<1, 256, 0, stream>>>(hdr, partials, xpart);
  k_pack<<<A_PACK_BLK + B_PACK_BLK, 256, 0, stream>>>((const float4*)x, (const float4*)w,
                                                      (int4v*)Apb, (int4v*)Bpb, hdr);
  k_gemm<<<(TOKENS / 256) * (OUT_F / 256), 512, 0, stream>>>(Apb, Bpb, out);
}